// Round 2
// baseline (299.723 us; speedup 1.0000x reference)
//
#include <hip/hip_runtime.h>
#include <hip/hip_bf16.h>
#include <cstdint>
#include <cstddef>

#define GS     128
#define OBS    1024
#define HSZ    256
#define OUTSZ  1024
#define NOUT   18
#define BATCH  256

typedef short  short8  __attribute__((ext_vector_type(8)));
typedef float  f32x4   __attribute__((ext_vector_type(4)));

__device__ __forceinline__ uint32_t f2bf_bits(float f) {
  uint32_t u = __builtin_bit_cast(uint32_t, f);
  return (u + 0x7fffu + ((u >> 16) & 1u)) >> 16;
}
__device__ __forceinline__ float bf_bits2f(uint32_t b) {
  return __builtin_bit_cast(float, b << 16);
}
__device__ __forceinline__ uint4 cvt8s(const float4 a, const float4 b) {
  float v[8] = {a.x, a.y, a.z, a.w, b.x, b.y, b.z, b.w};
  uint32_t h[8];
#pragma unroll
  for (int e = 0; e < 8; ++e) h[e] = f2bf_bits(v[e]);
  return make_uint4(h[0] | (h[1] << 16), h[2] | (h[3] << 16),
                    h[4] | (h[5] << 16), h[6] | (h[7] << 16));
}

// Raw barrier: ds ops drained (cross-wave LDS visibility), but VGPR-destined
// global loads stay IN FLIGHT across it (no vmcnt(0) drain, unlike
// __syncthreads). Compiler inserts counted vmcnt(N) at the actual uses.
__device__ __forceinline__ void bar_lds() {
  asm volatile("s_waitcnt lgkmcnt(0)" ::: "memory");
  __builtin_amdgcn_s_barrier();
  __builtin_amdgcn_sched_barrier(0);
}

// ---------------------------------------------------------------------------
// P0 (merged preps):
//  blk <128   : W0cat [1024][512] -> WtP packed bf16:
//               element (k,col) at ((k>>5)*512 + col)*32 + (k&31)
//  blk 128-131: WlT[19][1024] (Wl^T rows 0..17, Wv row 18)
//  blk 132-163: W1bf[512][1024] bf16 of [W1_rel ; W1_root]
// ---------------------------------------------------------------------------
__global__ __launch_bounds__(256) void prep_kernel(
    const float* __restrict__ W0_rel, const float* __restrict__ W0_root,
    ushort* __restrict__ WtP, const float* __restrict__ Wl,
    const float* __restrict__ Wv, float* __restrict__ WlT,
    const float* __restrict__ W1_rel, const float* __restrict__ W1_root,
    ushort* __restrict__ W1bf)
{
  __shared__ float T[64][65];
  const int blk = blockIdx.x;
  const int t = threadIdx.x;
  if (blk < 128) {
    const int k0 = (blk & 15) * 64;
    const int n0 = (blk >> 4) * 64;
    for (int idx = t; idx < 4096; idx += 256) {
      const int r = idx >> 6, c = idx & 63;
      const int n = n0 + c;
      T[r][c] = (n < HSZ) ? W0_rel[(size_t)(k0 + r) * HSZ + n]
                          : W0_root[(size_t)(k0 + r) * HSZ + (n - HSZ)];
    }
    __syncthreads();
    // packed 16B stores: thread handles 8 consecutive k for one col
    for (int idx = t; idx < 512; idx += 256) {
      const int nl = idx >> 3;       // col-local 0..63
      const int kc = idx & 7;        // k-chunk, 8 k's each
      uint32_t h[8];
#pragma unroll
      for (int e = 0; e < 8; ++e) h[e] = f2bf_bits(T[kc * 8 + e][nl]);
      const int kg = k0 + kc * 8;
      const uint4 w = make_uint4(h[0] | (h[1] << 16), h[2] | (h[3] << 16),
                                 h[4] | (h[5] << 16), h[6] | (h[7] << 16));
      *(uint4*)&WtP[((size_t)((kg >> 5) * 512 + n0 + nl)) * 32 + (kg & 31)] = w;
    }
  } else if (blk < 132) {
    const int o = (blk - 128) * 256 + t;
#pragma unroll
    for (int c = 0; c < NOUT; ++c)
      WlT[(size_t)c * OUTSZ + o] = Wl[(size_t)o * NOUT + c];
    WlT[(size_t)18 * OUTSZ + o] = Wv[o];
  } else {
    const int base = (blk - 132) * 16384;
    for (int it = 0; it < 64; ++it) {
      const int idx = base + it * 256 + t;
      const int k = idx >> 10, o = idx & 1023;
      const float v = (k < HSZ) ? W1_rel[(size_t)k * OUTSZ + o]
                                : W1_root[(size_t)(k - HSZ) * OUTSZ + o];
      W1bf[idx] = (ushort)f2bf_bits(v);
    }
  }
}

// ---------------------------------------------------------------------------
// MEGA kernel: one block of 512 threads (8 waves) per batch sample.
//  A: adjacency ballots -> row masks -> column masks (+forced entries)
//  B: gemm0 Ys = bf16((x @ [W0_rel|W0_root])^T): double-buffered As staging,
//     ONE raw barrier per K-step (ds drained, global loads live across it).
//     B-frags issued 1 step ahead, x loads 2 steps ahead; compiler emits
//     counted vmcnt before MFMA / stage-write (T4).
//  C: aggr P = A^T @ Yrel via MFMA; epilogue adds Yroot+b0, relu,
//     masked sum -> a1s / rns (wave owns 32 h's)
//  D: h1 = relu([a1|rn] @ W1bf + b1): waves 0-3 do a1 half, waves 4-7 rn
//     half, combine via LDS; logits/value via WlT
// ---------------------------------------------------------------------------
__global__ __launch_bounds__(512, 2) void mega_kernel(
    const float* __restrict__ flat, const float* __restrict__ nodes,
    const int* __restrict__ num_nodes, const int* __restrict__ adj,
    const float* __restrict__ b0, const ushort* __restrict__ WtP,
    const ushort* __restrict__ W1bf, const float* __restrict__ b1,
    const float* __restrict__ WlT, const float* __restrict__ bl,
    const float* __restrict__ bv, float* __restrict__ out)
{
  __shared__ alignas(16) char smem[135168];            // Ys region, 132 KB
  ushort (*Ys)[264]     = (ushort (*)[264])smem;       // [256][264]
  ushort (*As)[128][40] = (ushort (*)[128][40])smem;   // dbuf overlay, 20 KB
  float  (*part)[4]     = (float  (*)[4])smem;         // Phase D overlay, 4 KB
  __shared__ uint32_t rm[128][4];
  __shared__ uint32_t cmL[128][4];
  __shared__ float    a1s[256];
  __shared__ float    rns[256];
  __shared__ float    pl[19][4];

  const int b  = blockIdx.x;
  const int nb = num_nodes[b];
  const int t  = threadIdx.x;
  const int wv = t >> 6, lane = t & 63;
  const int ln = lane & 15, q = lane >> 4;

  // ---------------- Phase A: masks ----------------
#pragma unroll 4
  for (int i = 0; i < 16; ++i) {
    const int k = wv * 16 + i;
    const int* arow = adj + ((size_t)b * GS + k) * GS;
    const unsigned long long m0 = __ballot(arow[lane] != 0);
    const unsigned long long m1 = __ballot(arow[64 + lane] != 0);
    if (lane == 0) {
      rm[k][0] = (uint32_t)m0; rm[k][1] = (uint32_t)(m0 >> 32);
      rm[k][2] = (uint32_t)m1; rm[k][3] = (uint32_t)(m1 >> 32);
    }
  }
  __syncthreads();
  if (t < 128) {
    uint32_t c0 = 0, c1 = 0, c2 = 0, c3 = 0;
    const int w = t >> 5, sh = t & 31;
#pragma unroll 8
    for (int k = 0; k < 128; ++k) {
      const uint32_t bit = (rm[k][w] >> sh) & 1u;
      if (k < 32)      c0 |= bit << k;
      else if (k < 64) c1 |= bit << (k - 32);
      else if (k < 96) c2 |= bit << (k - 64);
      else             c3 |= bit << (k - 96);
    }
    cmL[t][0] = c0; cmL[t][1] = c1; cmL[t][2] = c2; cmL[t][3] = c3;
  }
  __syncthreads();
  if (t == 0) {
    cmL[nb][nb >> 5] |= 1u << (nb & 31);
    if (nb > 0) {
      cmL[nb - 1][nb >> 5] |= 1u << (nb & 31);
      cmL[nb][(nb - 1) >> 5] |= 1u << ((nb - 1) & 31);
    }
  }

  // ---------------- Phase B: gemm0 (dbuf, 1 raw barrier / K-step) -----------
  const int arow2 = t >> 2;            // staging row 0..127
  const int akb   = (t & 3) * 8;       // k-offset within 32
  const float* xsrc = ((arow2 == nb) ? (flat + (size_t)b * OBS)
                                     : (nodes + ((size_t)b * GS + arow2) * OBS)) + akb;
  // wave owns cat-cols [wv*64, +64)
  const ushort* bptr = WtP + ((size_t)(wv * 64 + ln)) * 32 + q * 8;

  f32x4 acc[4][8] = {};   // [jj: col-tile][ii: node-tile], 128 f32

  {
    const float4 c0 = *(const float4*)(xsrc);
    const float4 c1 = *(const float4*)(xsrc + 4);
    *(uint4*)&As[0][arow2][akb] = cvt8s(c0, c1);   // stage slice 0
  }
  short8 bc0 = *(const short8*)(bptr);             // B-frags slice 0
  short8 bc1 = *(const short8*)(bptr + 512);
  short8 bc2 = *(const short8*)(bptr + 1024);
  short8 bc3 = *(const short8*)(bptr + 1536);
  float4 gA = *(const float4*)(xsrc + 32);         // slice 1 data in flight
  float4 gB = *(const float4*)(xsrc + 36);
  bar_lds();

  for (int s = 0; s < 32; s += 2) {
    { // ---- even body: sigma = s. reads As[0], stages As[1] (slice s+1) ----
      const ushort* bp = bptr + (size_t)(s + 1) * 16384;  // B for slice s+1
      const short8 bn0 = *(const short8*)(bp);
      const short8 bn1 = *(const short8*)(bp + 512);
      const short8 bn2 = *(const short8*)(bp + 1024);
      const short8 bn3 = *(const short8*)(bp + 1536);
      float4 fA = {}, fB = {};
      if (s + 2 < 32) {                            // issue x for slice s+2
        fA = *(const float4*)(xsrc + (s + 2) * 32);
        fB = *(const float4*)(xsrc + (s + 2) * 32 + 4);
      }
      short8 ah[8];
#pragma unroll
      for (int ii = 0; ii < 8; ++ii)
        ah[ii] = *(const short8*)&As[0][ii * 16 + ln][q * 8];
#pragma unroll
      for (int ii = 0; ii < 8; ++ii) {
        acc[0][ii] = __builtin_amdgcn_mfma_f32_16x16x32_bf16(bc0, ah[ii], acc[0][ii], 0, 0, 0);
        acc[1][ii] = __builtin_amdgcn_mfma_f32_16x16x32_bf16(bc1, ah[ii], acc[1][ii], 0, 0, 0);
        acc[2][ii] = __builtin_amdgcn_mfma_f32_16x16x32_bf16(bc2, ah[ii], acc[2][ii], 0, 0, 0);
        acc[3][ii] = __builtin_amdgcn_mfma_f32_16x16x32_bf16(bc3, ah[ii], acc[3][ii], 0, 0, 0);
      }
      *(uint4*)&As[1][arow2][akb] = cvt8s(gA, gB); // stage slice s+1
      gA = fA; gB = fB;
      bc0 = bn0; bc1 = bn1; bc2 = bn2; bc3 = bn3;
      bar_lds();
    }
    { // ---- odd body: sigma = s+1. reads As[1], stages As[0] (slice s+2) ----
      short8 bn0 = {}, bn1 = {}, bn2 = {}, bn3 = {};
      if (s + 2 < 32) {                            // B for slice s+2
        const ushort* bp = bptr + (size_t)(s + 2) * 16384;
        bn0 = *(const short8*)(bp);
        bn1 = *(const short8*)(bp + 512);
        bn2 = *(const short8*)(bp + 1024);
        bn3 = *(const short8*)(bp + 1536);
      }
      float4 fA = {}, fB = {};
      if (s + 3 < 32) {                            // issue x for slice s+3
        fA = *(const float4*)(xsrc + (s + 3) * 32);
        fB = *(const float4*)(xsrc + (s + 3) * 32 + 4);
      }
      short8 ah[8];
#pragma unroll
      for (int ii = 0; ii < 8; ++ii)
        ah[ii] = *(const short8*)&As[1][ii * 16 + ln][q * 8];
#pragma unroll
      for (int ii = 0; ii < 8; ++ii) {
        acc[0][ii] = __builtin_amdgcn_mfma_f32_16x16x32_bf16(bc0, ah[ii], acc[0][ii], 0, 0, 0);
        acc[1][ii] = __builtin_amdgcn_mfma_f32_16x16x32_bf16(bc1, ah[ii], acc[1][ii], 0, 0, 0);
        acc[2][ii] = __builtin_amdgcn_mfma_f32_16x16x32_bf16(bc2, ah[ii], acc[2][ii], 0, 0, 0);
        acc[3][ii] = __builtin_amdgcn_mfma_f32_16x16x32_bf16(bc3, ah[ii], acc[3][ii], 0, 0, 0);
      }
      if (s + 2 < 32)
        *(uint4*)&As[0][arow2][akb] = cvt8s(gA, gB);   // stage slice s+2
      gA = fA; gB = fB;
      bc0 = bn0; bc1 = bn1; bc2 = bn2; bc3 = bn3;
      bar_lds();
    }
  }

  // epilogue -> Ys (As is dead; Ys overlays it)
#pragma unroll
  for (int jj = 0; jj < 4; ++jj) {
    const int cat = wv * 64 + jj * 16 + q * 4;    // +r; side uniform per tile
    const int h   = cat & 255;
    const int kof = (cat < 256) ? 0 : 128;
#pragma unroll
    for (int ii = 0; ii < 8; ++ii) {
      const int kk = kof + ii * 16 + ln;
#pragma unroll
      for (int r = 0; r < 4; ++r)
        Ys[h + r][kk] = (ushort)f2bf_bits(acc[jj][ii][r]);
    }
  }
  __syncthreads();

  // ---------------- Phase C: aggregation ----------------
  // wave wv owns h in [wv*32, +32)
  f32x4 acc2[8][2] = {};
#pragma unroll
  for (int ks = 0; ks < 4; ++ks) {
    const short8 bf0 = *(const short8*)&Ys[wv * 32 + ln][ks * 32 + q * 8];
    const short8 bf1 = *(const short8*)&Ys[wv * 32 + 16 + ln][ks * 32 + q * 8];
#pragma unroll
    for (int jt = 0; jt < 8; ++jt) {
      const uint32_t w = cmL[jt * 16 + ln][ks];
      const uint32_t byte_ = (w >> (q * 8)) & 0xFFu;
      short8 af;
#pragma unroll
      for (int i = 0; i < 8; ++i)
        af[i] = (short)(((byte_ >> i) & 1u) ? 0x3F80 : 0);
      acc2[jt][0] = __builtin_amdgcn_mfma_f32_16x16x32_bf16(af, bf0, acc2[jt][0], 0, 0, 0);
      acc2[jt][1] = __builtin_amdgcn_mfma_f32_16x16x32_bf16(af, bf1, acc2[jt][1], 0, 0, 0);
    }
  }

  const uint32_t S0 = cmL[nb][0], S1 = cmL[nb][1],
                 S2 = cmL[nb][2], S3 = cmL[nb][3];
  const float bb0 = b0[wv * 32 + ln];
  const float bb1 = b0[wv * 32 + 16 + ln];

  float asum0 = 0.f, asum1 = 0.f;
#pragma unroll
  for (int jt = 0; jt < 8; ++jt)
#pragma unroll
    for (int r = 0; r < 4; ++r) {
      const int j = jt * 16 + q * 4 + r;
      const uint32_t Sw = (j < 32) ? S0 : (j < 64) ? S1 : (j < 96) ? S2 : S3;
      const bool sj = (Sw >> (j & 31)) & 1u;
      const bool isn = (j == nb);
      {
        const int hl = wv * 32 + ln;
        const float yroot = bf_bits2f(Ys[hl][128 + j]);
        const float v = fmaxf(bb0 + yroot + acc2[jt][0][r], 0.f);
        if (sj) asum0 += v;
        if (isn) rns[hl] = v;
      }
      {
        const int hl = wv * 32 + 16 + ln;
        const float yroot = bf_bits2f(Ys[hl][128 + j]);
        const float v = fmaxf(bb1 + yroot + acc2[jt][1][r], 0.f);
        if (sj) asum1 += v;
        if (isn) rns[hl] = v;
      }
    }
  asum0 += __shfl_down(asum0, 32);
  asum0 += __shfl_down(asum0, 16);
  asum1 += __shfl_down(asum1, 32);
  asum1 += __shfl_down(asum1, 16);
  if (q == 0) {
    a1s[wv * 32 + ln]      = asum0;
    a1s[wv * 32 + 16 + ln] = asum1;
  }
  __syncthreads();

  // ---------------- Phase D: gemm1 + head (split across wave halves) --------
  const int oh = t >> 8;               // 0: a1 half (k 0..255), 1: rn half
  const int o4 = (t & 255) * 4;
  float4 a = make_float4(0.f, 0.f, 0.f, 0.f);
  if (oh == 0) a = *(const float4*)&b1[o4];
  const ushort* wp = W1bf + (size_t)oh * 256 * OUTSZ + o4;
  const float* sv = oh ? rns : a1s;
#pragma unroll 8
  for (int k = 0; k < 256; ++k) {
    const ushort4 w4 = *(const ushort4*)(wp + (size_t)k * OUTSZ);
    const float s = sv[k];
    a.x = fmaf(s, bf_bits2f(w4.x), a.x);
    a.y = fmaf(s, bf_bits2f(w4.y), a.y);
    a.z = fmaf(s, bf_bits2f(w4.z), a.z);
    a.w = fmaf(s, bf_bits2f(w4.w), a.w);
  }
  if (oh == 1) *(float4*)&part[t & 255][0] = a;   // Ys dead; part overlays it
  __syncthreads();
  if (oh == 0) {
    const float4 pb = *(const float4*)&part[t & 255][0];
    a.x = fmaxf(a.x + pb.x, 0.f);
    a.y = fmaxf(a.y + pb.y, 0.f);
    a.z = fmaxf(a.z + pb.z, 0.f);
    a.w = fmaxf(a.w + pb.w, 0.f);
    float p[19];
#pragma unroll
    for (int c = 0; c < 19; ++c) {
      const float4 w = *(const float4*)&WlT[(size_t)c * OUTSZ + o4];
      p[c] = a.x * w.x + a.y * w.y + a.z * w.z + a.w * w.w;
    }
#pragma unroll
    for (int c = 0; c < 19; ++c) {
      float v = p[c];
      v += __shfl_down(v, 32); v += __shfl_down(v, 16);
      v += __shfl_down(v, 8);  v += __shfl_down(v, 4);
      v += __shfl_down(v, 2);  v += __shfl_down(v, 1);
      if (lane == 0) pl[c][wv] = v;
    }
  }
  __syncthreads();
  if (t < 19) {
    const float s = pl[t][0] + pl[t][1] + pl[t][2] + pl[t][3];
    if (t < NOUT) out[(size_t)b * NOUT + t] = s + bl[t];
    else          out[(size_t)BATCH * NOUT + b] = s + bv[0];
  }
}

// ---------------------------------------------------------------------------
extern "C" void kernel_launch(void* const* d_in, const int* in_sizes, int n_in,
                              void* d_out, int out_size, void* d_ws, size_t ws_size,
                              hipStream_t stream)
{
  const float* flat      = (const float*)d_in[0];
  const float* nodes     = (const float*)d_in[1];
  const int*   num_nodes = (const int*)  d_in[2];
  const int*   adj       = (const int*)  d_in[3];
  const float* W0_rel    = (const float*)d_in[5];
  const float* b0        = (const float*)d_in[6];
  const float* W0_root   = (const float*)d_in[7];
  const float* W1_rel    = (const float*)d_in[8];
  const float* b1        = (const float*)d_in[9];
  const float* W1_root   = (const float*)d_in[10];
  const float* Wl        = (const float*)d_in[11];
  const float* bl        = (const float*)d_in[12];
  const float* Wv        = (const float*)d_in[13];
  const float* bv        = (const float*)d_in[14];
  float* out = (float*)d_out;

  char* ws = (char*)d_ws;
  ushort* WtP  = (ushort*)ws;  ws += (size_t)512 * OBS * 2;   // 1 MiB
  float*  WlT  = (float*)ws;   ws += (size_t)19 * OUTSZ * 4;  // 76 KiB
  ushort* W1bf = (ushort*)ws;  ws += (size_t)512 * OUTSZ * 2; // 1 MiB

  prep_kernel<<<164, 256, 0, stream>>>(
      W0_rel, W0_root, WtP, Wl, Wv, WlT, W1_rel, W1_root, W1bf);
  mega_kernel<<<BATCH, 512, 0, stream>>>(
      flat, nodes, num_nodes, adj, b0, WtP, W1bf, b1, WlT, bl, bv, out);
}

// Round 3
// 292.891 us; speedup vs baseline: 1.0233x; 1.0233x over previous
//
#include <hip/hip_runtime.h>
#include <hip/hip_bf16.h>
#include <cstdint>
#include <cstddef>

#define GS     128
#define OBS    1024
#define HSZ    256
#define OUTSZ  1024
#define NOUT   18
#define BATCH  256

typedef short  short8  __attribute__((ext_vector_type(8)));
typedef float  f32x4   __attribute__((ext_vector_type(4)));

__device__ __forceinline__ uint32_t f2bf_bits(float f) {
  uint32_t u = __builtin_bit_cast(uint32_t, f);
  return (u + 0x7fffu + ((u >> 16) & 1u)) >> 16;
}
__device__ __forceinline__ float bf_bits2f(uint32_t b) {
  return __builtin_bit_cast(float, b << 16);
}
__device__ __forceinline__ uint4 cvt8s(const float4 a, const float4 b) {
  float v[8] = {a.x, a.y, a.z, a.w, b.x, b.y, b.z, b.w};
  uint32_t h[8];
#pragma unroll
  for (int e = 0; e < 8; ++e) h[e] = f2bf_bits(v[e]);
  return make_uint4(h[0] | (h[1] << 16), h[2] | (h[3] << 16),
                    h[4] | (h[5] << 16), h[6] | (h[7] << 16));
}

// Raw barrier: ds ops drained (cross-wave LDS visibility), global loads stay
// in flight across it.
__device__ __forceinline__ void bar_lds() {
  asm volatile("s_waitcnt lgkmcnt(0)" ::: "memory");
  __builtin_amdgcn_s_barrier();
  __builtin_amdgcn_sched_barrier(0);
}

// ---------------------------------------------------------------------------
// P0 (merged preps):
//  blk <128   : W0cat [1024][512] -> WtP packed bf16:
//               element (k,col) at ((k>>5)*512 + col)*32 + (k&31)
//  blk 128-131: WlT[19][1024] (Wl^T rows 0..17, Wv row 18)
//  blk 132-163: W1bf[512][1024] bf16 of [W1_rel ; W1_root]
// ---------------------------------------------------------------------------
__global__ __launch_bounds__(256) void prep_kernel(
    const float* __restrict__ W0_rel, const float* __restrict__ W0_root,
    ushort* __restrict__ WtP, const float* __restrict__ Wl,
    const float* __restrict__ Wv, float* __restrict__ WlT,
    const float* __restrict__ W1_rel, const float* __restrict__ W1_root,
    ushort* __restrict__ W1bf)
{
  __shared__ float T[64][65];
  const int blk = blockIdx.x;
  const int t = threadIdx.x;
  if (blk < 128) {
    const int k0 = (blk & 15) * 64;
    const int n0 = (blk >> 4) * 64;
    for (int idx = t; idx < 4096; idx += 256) {
      const int r = idx >> 6, c = idx & 63;
      const int n = n0 + c;
      T[r][c] = (n < HSZ) ? W0_rel[(size_t)(k0 + r) * HSZ + n]
                          : W0_root[(size_t)(k0 + r) * HSZ + (n - HSZ)];
    }
    __syncthreads();
    // packed 16B stores: thread handles 8 consecutive k for one col
    for (int idx = t; idx < 512; idx += 256) {
      const int nl = idx >> 3;       // col-local 0..63
      const int kc = idx & 7;        // k-chunk, 8 k's each
      uint32_t h[8];
#pragma unroll
      for (int e = 0; e < 8; ++e) h[e] = f2bf_bits(T[kc * 8 + e][nl]);
      const int kg = k0 + kc * 8;
      const uint4 w = make_uint4(h[0] | (h[1] << 16), h[2] | (h[3] << 16),
                                 h[4] | (h[5] << 16), h[6] | (h[7] << 16));
      *(uint4*)&WtP[((size_t)((kg >> 5) * 512 + n0 + nl)) * 32 + (kg & 31)] = w;
    }
  } else if (blk < 132) {
    const int o = (blk - 128) * 256 + t;
#pragma unroll
    for (int c = 0; c < NOUT; ++c)
      WlT[(size_t)c * OUTSZ + o] = Wl[(size_t)o * NOUT + c];
    WlT[(size_t)18 * OUTSZ + o] = Wv[o];
  } else {
    const int base = (blk - 132) * 16384;
    for (int it = 0; it < 64; ++it) {
      const int idx = base + it * 256 + t;
      const int k = idx >> 10, o = idx & 1023;
      const float v = (k < HSZ) ? W1_rel[(size_t)k * OUTSZ + o]
                                : W1_root[(size_t)(k - HSZ) * OUTSZ + o];
      W1bf[idx] = (ushort)f2bf_bits(v);
    }
  }
}

// ---------------------------------------------------------------------------
// MEGA kernel: one block of 512 threads (8 waves) per batch sample.
//  A: adjacency masks — all 32 loads batched into regs first (1 round trip)
//  B: gemm0 Ys = bf16((x @ [W0_rel|W0_root])^T): BK=64 double-buffered
//     staging (As[2][128][72], 144B rows: 16B-aligned, 2-way banks), 16
//     raw barriers; 64 MFMA/wave/step; x prefetched 1 step ahead, slice-B
//     frags issued early in-step, next slice-A mid-step.
//  C: aggr P = A^T @ Yrel via MFMA; epilogue adds Yroot+b0, relu,
//     masked sum -> a1s / rns (wave owns 32 h's)
//  D: h1 = relu([a1|rn] @ W1bf + b1): thread-halves split k; combine in LDS;
//     logits/value via WlT
// ---------------------------------------------------------------------------
__global__ __launch_bounds__(512, 2) void mega_kernel(
    const float* __restrict__ flat, const float* __restrict__ nodes,
    const int* __restrict__ num_nodes, const int* __restrict__ adj,
    const float* __restrict__ b0, const ushort* __restrict__ WtP,
    const ushort* __restrict__ W1bf, const float* __restrict__ b1,
    const float* __restrict__ WlT, const float* __restrict__ bl,
    const float* __restrict__ bv, float* __restrict__ out)
{
  __shared__ alignas(16) char smem[135168];            // Ys region, 132 KB
  ushort (*Ys)[264]     = (ushort (*)[264])smem;       // [256][264]
  ushort (*As)[128][72] = (ushort (*)[128][72])smem;   // dbuf overlay, 36 KB
  float  (*part)[4]     = (float  (*)[4])smem;         // Phase D overlay, 4 KB
  __shared__ uint32_t rm[128][4];
  __shared__ uint32_t cmL[128][4];
  __shared__ float    a1s[256];
  __shared__ float    rns[256];
  __shared__ float    pl[19][4];

  const int b  = blockIdx.x;
  const int nb = num_nodes[b];
  const int t  = threadIdx.x;
  const int wv = t >> 6, lane = t & 63;
  const int ln = lane & 15, q = lane >> 4;

  // ---------------- Phase A: masks (batched loads) ----------------
  {
    const int* abase = adj + ((size_t)b * GS + wv * 16) * GS;
    int va[16], vb[16];
#pragma unroll
    for (int i = 0; i < 16; ++i) {
      va[i] = abase[i * GS + lane];
      vb[i] = abase[i * GS + 64 + lane];
    }
#pragma unroll
    for (int i = 0; i < 16; ++i) {
      const int k = wv * 16 + i;
      const unsigned long long m0 = __ballot(va[i] != 0);
      const unsigned long long m1 = __ballot(vb[i] != 0);
      if (lane == 0) {
        rm[k][0] = (uint32_t)m0; rm[k][1] = (uint32_t)(m0 >> 32);
        rm[k][2] = (uint32_t)m1; rm[k][3] = (uint32_t)(m1 >> 32);
      }
    }
  }
  __syncthreads();
  if (t < 128) {
    uint32_t c0 = 0, c1 = 0, c2 = 0, c3 = 0;
    const int w = t >> 5, sh = t & 31;
#pragma unroll 8
    for (int k = 0; k < 128; ++k) {
      const uint32_t bit = (rm[k][w] >> sh) & 1u;
      if (k < 32)      c0 |= bit << k;
      else if (k < 64) c1 |= bit << (k - 32);
      else if (k < 96) c2 |= bit << (k - 64);
      else             c3 |= bit << (k - 96);
    }
    cmL[t][0] = c0; cmL[t][1] = c1; cmL[t][2] = c2; cmL[t][3] = c3;
  }
  __syncthreads();
  if (t == 0) {
    cmL[nb][nb >> 5] |= 1u << (nb & 31);
    if (nb > 0) {
      cmL[nb - 1][nb >> 5] |= 1u << (nb & 31);
      cmL[nb][(nb - 1) >> 5] |= 1u << ((nb - 1) & 31);
    }
  }

  // ---------------- Phase B: gemm0 (BK=64, dbuf, 16 raw barriers) ----------
  const int arow2 = t >> 2;            // staging row 0..127
  const int akb   = (t & 3) * 16;      // k-offset within 64 (16 k's/thread)
  const float* xsrc = ((arow2 == nb) ? (flat + (size_t)b * OBS)
                                     : (nodes + ((size_t)b * GS + arow2) * OBS)) + akb;
  // wave owns cat-cols [wv*64, +64); slice sl at +sl*16384
  const ushort* bptr = WtP + ((size_t)(wv * 64 + ln)) * 32 + q * 8;

  f32x4 acc[4][8] = {};   // [jj: col-tile][ii: node-tile], 128 f32

  { // stage step 0 (k 0..63)
    const float4 a0 = *(const float4*)(xsrc);
    const float4 a1 = *(const float4*)(xsrc + 4);
    const float4 a2 = *(const float4*)(xsrc + 8);
    const float4 a3 = *(const float4*)(xsrc + 12);
    *(uint4*)&As[0][arow2][akb]     = cvt8s(a0, a1);
    *(uint4*)&As[0][arow2][akb + 8] = cvt8s(a2, a3);
  }
  // x for step 1 in flight
  float4 g0 = *(const float4*)(xsrc + 64);
  float4 g1 = *(const float4*)(xsrc + 68);
  float4 g2 = *(const float4*)(xsrc + 72);
  float4 g3 = *(const float4*)(xsrc + 76);
  // B frags, slice 0 (k 0..31)
  short8 bA0 = *(const short8*)(bptr);
  short8 bA1 = *(const short8*)(bptr + 512);
  short8 bA2 = *(const short8*)(bptr + 1024);
  short8 bA3 = *(const short8*)(bptr + 1536);
  bar_lds();

  for (int s = 0; s < 16; ++s) {
    const int buf = s & 1;
    // slice-B frags (k 32..63 of this step) — issue early, used after MFMA1
    const ushort* bpB = bptr + ((size_t)(2 * s + 1)) * 16384;
    const short8 bB0 = *(const short8*)(bpB);
    const short8 bB1 = *(const short8*)(bpB + 512);
    const short8 bB2 = *(const short8*)(bpB + 1024);
    const short8 bB3 = *(const short8*)(bpB + 1536);
    // ah slice A (k-local 0..31)
    short8 ah[8];
#pragma unroll
    for (int ii = 0; ii < 8; ++ii)
      ah[ii] = *(const short8*)&As[buf][ii * 16 + ln][q * 8];
#pragma unroll
    for (int ii = 0; ii < 8; ++ii) {
      acc[0][ii] = __builtin_amdgcn_mfma_f32_16x16x32_bf16(bA0, ah[ii], acc[0][ii], 0, 0, 0);
      acc[1][ii] = __builtin_amdgcn_mfma_f32_16x16x32_bf16(bA1, ah[ii], acc[1][ii], 0, 0, 0);
      acc[2][ii] = __builtin_amdgcn_mfma_f32_16x16x32_bf16(bA2, ah[ii], acc[2][ii], 0, 0, 0);
      acc[3][ii] = __builtin_amdgcn_mfma_f32_16x16x32_bf16(bA3, ah[ii], acc[3][ii], 0, 0, 0);
    }
    // ah slice B (k-local 32..63)
    short8 ah2[8];
#pragma unroll
    for (int ii = 0; ii < 8; ++ii)
      ah2[ii] = *(const short8*)&As[buf][ii * 16 + ln][32 + q * 8];
    // stage x(s+1) into other buffer (g loaded one step ago)
    if (s + 1 < 16) {
      *(uint4*)&As[buf ^ 1][arow2][akb]     = cvt8s(g0, g1);
      *(uint4*)&As[buf ^ 1][arow2][akb + 8] = cvt8s(g2, g3);
    }
    // prefetch next-step slice-A frags
    short8 nA0 = {}, nA1 = {}, nA2 = {}, nA3 = {};
    if (s + 1 < 16) {
      const ushort* bpA = bptr + ((size_t)(2 * s + 2)) * 16384;
      nA0 = *(const short8*)(bpA);
      nA1 = *(const short8*)(bpA + 512);
      nA2 = *(const short8*)(bpA + 1024);
      nA3 = *(const short8*)(bpA + 1536);
    }
    // issue x(s+2)
    if (s + 2 < 16) {
      g0 = *(const float4*)(xsrc + (s + 2) * 64);
      g1 = *(const float4*)(xsrc + (s + 2) * 64 + 4);
      g2 = *(const float4*)(xsrc + (s + 2) * 64 + 8);
      g3 = *(const float4*)(xsrc + (s + 2) * 64 + 12);
    }
#pragma unroll
    for (int ii = 0; ii < 8; ++ii) {
      acc[0][ii] = __builtin_amdgcn_mfma_f32_16x16x32_bf16(bB0, ah2[ii], acc[0][ii], 0, 0, 0);
      acc[1][ii] = __builtin_amdgcn_mfma_f32_16x16x32_bf16(bB1, ah2[ii], acc[1][ii], 0, 0, 0);
      acc[2][ii] = __builtin_amdgcn_mfma_f32_16x16x32_bf16(bB2, ah2[ii], acc[2][ii], 0, 0, 0);
      acc[3][ii] = __builtin_amdgcn_mfma_f32_16x16x32_bf16(bB3, ah2[ii], acc[3][ii], 0, 0, 0);
    }
    bA0 = nA0; bA1 = nA1; bA2 = nA2; bA3 = nA3;
    bar_lds();
  }

  // epilogue -> Ys (As is dead; Ys overlays it)
#pragma unroll
  for (int jj = 0; jj < 4; ++jj) {
    const int cat = wv * 64 + jj * 16 + q * 4;    // +r; side uniform per tile
    const int h   = cat & 255;
    const int kof = (cat < 256) ? 0 : 128;
#pragma unroll
    for (int ii = 0; ii < 8; ++ii) {
      const int kk = kof + ii * 16 + ln;
#pragma unroll
      for (int r = 0; r < 4; ++r)
        Ys[h + r][kk] = (ushort)f2bf_bits(acc[jj][ii][r]);
    }
  }
  __syncthreads();

  // ---------------- Phase C: aggregation ----------------
  // wave wv owns h in [wv*32, +32)
  f32x4 acc2[8][2] = {};
#pragma unroll
  for (int ks = 0; ks < 4; ++ks) {
    const short8 bf0 = *(const short8*)&Ys[wv * 32 + ln][ks * 32 + q * 8];
    const short8 bf1 = *(const short8*)&Ys[wv * 32 + 16 + ln][ks * 32 + q * 8];
#pragma unroll
    for (int jt = 0; jt < 8; ++jt) {
      const uint32_t w = cmL[jt * 16 + ln][ks];
      const uint32_t byte_ = (w >> (q * 8)) & 0xFFu;
      short8 af;
#pragma unroll
      for (int i = 0; i < 8; ++i)
        af[i] = (short)(((byte_ >> i) & 1u) ? 0x3F80 : 0);
      acc2[jt][0] = __builtin_amdgcn_mfma_f32_16x16x32_bf16(af, bf0, acc2[jt][0], 0, 0, 0);
      acc2[jt][1] = __builtin_amdgcn_mfma_f32_16x16x32_bf16(af, bf1, acc2[jt][1], 0, 0, 0);
    }
  }

  const uint32_t S0 = cmL[nb][0], S1 = cmL[nb][1],
                 S2 = cmL[nb][2], S3 = cmL[nb][3];
  const float bb0 = b0[wv * 32 + ln];
  const float bb1 = b0[wv * 32 + 16 + ln];

  float asum0 = 0.f, asum1 = 0.f;
#pragma unroll
  for (int jt = 0; jt < 8; ++jt)
#pragma unroll
    for (int r = 0; r < 4; ++r) {
      const int j = jt * 16 + q * 4 + r;
      const uint32_t Sw = (j < 32) ? S0 : (j < 64) ? S1 : (j < 96) ? S2 : S3;
      const bool sj = (Sw >> (j & 31)) & 1u;
      const bool isn = (j == nb);
      {
        const int hl = wv * 32 + ln;
        const float yroot = bf_bits2f(Ys[hl][128 + j]);
        const float v = fmaxf(bb0 + yroot + acc2[jt][0][r], 0.f);
        if (sj) asum0 += v;
        if (isn) rns[hl] = v;
      }
      {
        const int hl = wv * 32 + 16 + ln;
        const float yroot = bf_bits2f(Ys[hl][128 + j]);
        const float v = fmaxf(bb1 + yroot + acc2[jt][1][r], 0.f);
        if (sj) asum1 += v;
        if (isn) rns[hl] = v;
      }
    }
  asum0 += __shfl_down(asum0, 32);
  asum0 += __shfl_down(asum0, 16);
  asum1 += __shfl_down(asum1, 32);
  asum1 += __shfl_down(asum1, 16);
  if (q == 0) {
    a1s[wv * 32 + ln]      = asum0;
    a1s[wv * 32 + 16 + ln] = asum1;
  }
  __syncthreads();

  // ---------------- Phase D: gemm1 + head (split across wave halves) --------
  const int oh = t >> 8;               // 0: a1 half (k 0..255), 1: rn half
  const int o4 = (t & 255) * 4;
  float4 a = make_float4(0.f, 0.f, 0.f, 0.f);
  if (oh == 0) a = *(const float4*)&b1[o4];
  const ushort* wp = W1bf + (size_t)oh * 256 * OUTSZ + o4;
  const float* sv = oh ? rns : a1s;
#pragma unroll 8
  for (int k = 0; k < 256; ++k) {
    const ushort4 w4 = *(const ushort4*)(wp + (size_t)k * OUTSZ);
    const float s = sv[k];
    a.x = fmaf(s, bf_bits2f(w4.x), a.x);
    a.y = fmaf(s, bf_bits2f(w4.y), a.y);
    a.z = fmaf(s, bf_bits2f(w4.z), a.z);
    a.w = fmaf(s, bf_bits2f(w4.w), a.w);
  }
  if (oh == 1) *(float4*)&part[t & 255][0] = a;   // Ys dead; part overlays it
  __syncthreads();
  if (oh == 0) {
    const float4 pb = *(const float4*)&part[t & 255][0];
    a.x = fmaxf(a.x + pb.x, 0.f);
    a.y = fmaxf(a.y + pb.y, 0.f);
    a.z = fmaxf(a.z + pb.z, 0.f);
    a.w = fmaxf(a.w + pb.w, 0.f);
    float p[19];
#pragma unroll
    for (int c = 0; c < 19; ++c) {
      const float4 w = *(const float4*)&WlT[(size_t)c * OUTSZ + o4];
      p[c] = a.x * w.x + a.y * w.y + a.z * w.z + a.w * w.w;
    }
#pragma unroll
    for (int c = 0; c < 19; ++c) {
      float v = p[c];
      v += __shfl_down(v, 32); v += __shfl_down(v, 16);
      v += __shfl_down(v, 8);  v += __shfl_down(v, 4);
      v += __shfl_down(v, 2);  v += __shfl_down(v, 1);
      if (lane == 0) pl[c][wv] = v;
    }
  }
  __syncthreads();
  if (t < 19) {
    const float s = pl[t][0] + pl[t][1] + pl[t][2] + pl[t][3];
    if (t < NOUT) out[(size_t)b * NOUT + t] = s + bl[t];
    else          out[(size_t)BATCH * NOUT + b] = s + bv[0];
  }
}

// ---------------------------------------------------------------------------
extern "C" void kernel_launch(void* const* d_in, const int* in_sizes, int n_in,
                              void* d_out, int out_size, void* d_ws, size_t ws_size,
                              hipStream_t stream)
{
  const float* flat      = (const float*)d_in[0];
  const float* nodes     = (const float*)d_in[1];
  const int*   num_nodes = (const int*)  d_in[2];
  const int*   adj       = (const int*)  d_in[3];
  const float* W0_rel    = (const float*)d_in[5];
  const float* b0        = (const float*)d_in[6];
  const float* W0_root   = (const float*)d_in[7];
  const float* W1_rel    = (const float*)d_in[8];
  const float* b1        = (const float*)d_in[9];
  const float* W1_root   = (const float*)d_in[10];
  const float* Wl        = (const float*)d_in[11];
  const float* bl        = (const float*)d_in[12];
  const float* Wv        = (const float*)d_in[13];
  const float* bv        = (const float*)d_in[14];
  float* out = (float*)d_out;

  char* ws = (char*)d_ws;
  ushort* WtP  = (ushort*)ws;  ws += (size_t)512 * OBS * 2;   // 1 MiB
  float*  WlT  = (float*)ws;   ws += (size_t)19 * OUTSZ * 4;  // 76 KiB
  ushort* W1bf = (ushort*)ws;  ws += (size_t)512 * OUTSZ * 2; // 1 MiB

  prep_kernel<<<164, 256, 0, stream>>>(
      W0_rel, W0_root, WtP, Wl, Wv, WlT, W1_rel, W1_root, W1bf);
  mega_kernel<<<BATCH, 512, 0, stream>>>(
      flat, nodes, num_nodes, adj, b0, WtP, W1bf, b1, WlT, bl, bv, out);
}